// Round 5
// baseline (528.600 us; speedup 1.0000x reference)
//
#include <hip/hip_runtime.h>
#include <math.h>

// Problem constants
#define NB   32768
#define AG   6
#define LL   225
#define DD   128
#define EE   5
#define NOUT 5
#define ADIM 64

// Workspace layout (floats)
#define WS_M   0        // 128*128  : M = q_w @ k_w^T / 8   (row-major [d1][d2])
#define WS_W1T 16384    // 5*128    : W1t[o*128+d] = sum_e fc_w[(e*128+d)*5+o]
#define WS_F2T 17024    // 25*128   : F2t[(e*5+o)*128+d] = fc_w[(640+e*128+d)*5+o]

// Tiling: block = 256 thr = 4 waves; wave = 4 samples (4 groups x 16 lanes);
// lane owns 8 cols: {4i..4i+3} u {64+4i..64+4i+3}, i = lane&15.
// NO LDS staging: obs via 16-lane-broadcast global loads (L1), enc_w streamed
// from L2 (115 KB, fully L2-resident). LDS = phase-2 slab only. No barriers.
#define SBLK 16          // samples per block
#define LDS_FLOATS 6144  // 4 waves * 1536 floats = 24,576 B

__global__ void precompute_kernel(const float* __restrict__ q_w,
                                  const float* __restrict__ k_w,
                                  const float* __restrict__ fc_w,
                                  float* __restrict__ ws) {
    int b = blockIdx.x;
    int t = threadIdx.x;
    if (b < 128) {
        float s = 0.f;
        #pragma unroll 8
        for (int j = 0; j < ADIM; ++j)
            s = fmaf(q_w[b * ADIM + j], k_w[t * ADIM + j], s);
        ws[WS_M + b * 128 + t] = s * 0.125f;
    } else {
        int d = t;
        #pragma unroll
        for (int o = 0; o < NOUT; ++o) {
            float s = 0.f;
            #pragma unroll
            for (int e = 0; e < EE; ++e)
                s += fc_w[(e * 128 + d) * NOUT + o];
            ws[WS_W1T + o * 128 + d] = s;
            #pragma unroll
            for (int e = 0; e < EE; ++e)
                ws[WS_F2T + (e * 5 + o) * 128 + d] = fc_w[(640 + e * 128 + d) * NOUT + o];
        }
    }
}

__global__ __launch_bounds__(256, 2)
void policy_kernel(const float* __restrict__ obs,
                   const float* __restrict__ enc_w,
                   const float* __restrict__ enc_b,
                   const float* __restrict__ fc_b,
                   const float* __restrict__ u,
                   const float* __restrict__ ws,
                   int* __restrict__ out) {
    __shared__ float lds[LDS_FLOATS];
    const int tid  = threadIdx.x;
    const int lane = tid & 63;
    const int w    = tid >> 6;
    const int g    = lane >> 4;      // sample group 0..3
    const int ii   = lane & 15;      // col sub-index
    const int bs0  = blockIdx.x * SBLK;
    const int samp = w * 4 + g;      // block-local sample

    float acc[AG][8];                // 48 acc regs; cols {4ii..} and {64+4ii..}
    #pragma unroll
    for (int a = 0; a < AG; ++a)
        #pragma unroll
        for (int c = 0; c < 8; ++c) acc[a][c] = 0.f;

    // This sample's obs base — uniform across the 16 lanes of the group.
    const float* obs_s = obs + (size_t)(bs0 + samp) * (AG * LL);
    const float* ewp   = enc_w + 4 * ii;   // lane's lo-column pointer

    // ---- encoder: 56 l-quads + tail l=224, everything from global ----
    #pragma unroll 1
    for (int q = 0; q < 56; ++q) {
        const int l0 = 4 * q;
        float4 ov[AG];
        #pragma unroll
        for (int a = 0; a < AG; ++a)
            ov[a] = *(const float4*)&obs_s[a * LL + l0];   // 16-lane broadcast

        #pragma unroll
        for (int dl = 0; dl < 4; ++dl) {
            const float4 lo = *(const float4*)&ewp[(size_t)(l0 + dl) * DD];
            const float4 hi = *(const float4*)&ewp[(size_t)(l0 + dl) * DD + 64];
            #pragma unroll
            for (int a = 0; a < AG; ++a) {
                const float o4 = (dl == 0) ? ov[a].x : (dl == 1) ? ov[a].y
                               : (dl == 2) ? ov[a].z : ov[a].w;
                acc[a][0] = fmaf(o4, lo.x, acc[a][0]);
                acc[a][1] = fmaf(o4, lo.y, acc[a][1]);
                acc[a][2] = fmaf(o4, lo.z, acc[a][2]);
                acc[a][3] = fmaf(o4, lo.w, acc[a][3]);
                acc[a][4] = fmaf(o4, hi.x, acc[a][4]);
                acc[a][5] = fmaf(o4, hi.y, acc[a][5]);
                acc[a][6] = fmaf(o4, hi.z, acc[a][6]);
                acc[a][7] = fmaf(o4, hi.w, acc[a][7]);
            }
        }
    }
    {   // tail l = 224
        const float4 lo = *(const float4*)&ewp[(size_t)224 * DD];
        const float4 hi = *(const float4*)&ewp[(size_t)224 * DD + 64];
        #pragma unroll
        for (int a = 0; a < AG; ++a) {
            const float o4 = obs_s[a * LL + 224];
            acc[a][0] = fmaf(o4, lo.x, acc[a][0]);
            acc[a][1] = fmaf(o4, lo.y, acc[a][1]);
            acc[a][2] = fmaf(o4, lo.z, acc[a][2]);
            acc[a][3] = fmaf(o4, lo.w, acc[a][3]);
            acc[a][4] = fmaf(o4, hi.x, acc[a][4]);
            acc[a][5] = fmaf(o4, hi.y, acc[a][5]);
            acc[a][6] = fmaf(o4, hi.z, acc[a][6]);
            acc[a][7] = fmaf(o4, hi.w, acc[a][7]);
        }
    }

    // ---- bias + relu in place ----
    {
        float4 bl = *(const float4*)&enc_b[4 * ii];
        float4 bh = *(const float4*)&enc_b[64 + 4 * ii];
        #pragma unroll
        for (int a = 0; a < AG; ++a) {
            acc[a][0] = fmaxf(acc[a][0] + bl.x, 0.f);
            acc[a][1] = fmaxf(acc[a][1] + bl.y, 0.f);
            acc[a][2] = fmaxf(acc[a][2] + bl.z, 0.f);
            acc[a][3] = fmaxf(acc[a][3] + bl.w, 0.f);
            acc[a][4] = fmaxf(acc[a][4] + bh.x, 0.f);
            acc[a][5] = fmaxf(acc[a][5] + bh.y, 0.f);
            acc[a][6] = fmaxf(acc[a][6] + bh.z, 0.f);
            acc[a][7] = fmaxf(acc[a][7] + bh.w, 0.f);
        }
    }

    // ---- phase 2: 2 passes of 2 samples through a per-wave 1536-float slab ----
    // (per-wave slab, same-wave LDS write->read ordered via lgkmcnt: no barriers)
    const float* Mw  = ws + WS_M;
    const int c0   = 2 * lane;       // phase-2 col pair
    const int slab = w * 1536;

    #pragma unroll 1
    for (int p = 0; p < 2; ++p) {
        // groups 2p, 2p+1 publish their relu'd enc rows
        if ((g >> 1) == p) {
            const int sb = slab + (g & 1) * 768;
            #pragma unroll
            for (int a = 0; a < AG; ++a) {
                *(float4*)&lds[sb + a * DD + 4 * ii] =
                    make_float4(acc[a][0], acc[a][1], acc[a][2], acc[a][3]);
                *(float4*)&lds[sb + a * DD + 64 + 4 * ii] =
                    make_float4(acc[a][4], acc[a][5], acc[a][6], acc[a][7]);
            }
        }

        // t = ag_e @ M for both samples
        float t0[2] = {0.f, 0.f}, t1[2] = {0.f, 0.f};
        #pragma unroll 4
        for (int d = 0; d < DD; d += 4) {
            float4 a0 = *(const float4*)&lds[slab + d];
            float4 a1 = *(const float4*)&lds[slab + 768 + d];
            float2 m0 = *(const float2*)&Mw[(size_t)(d + 0) * DD + c0];
            float2 m1 = *(const float2*)&Mw[(size_t)(d + 1) * DD + c0];
            float2 m2 = *(const float2*)&Mw[(size_t)(d + 2) * DD + c0];
            float2 m3 = *(const float2*)&Mw[(size_t)(d + 3) * DD + c0];
            t0[0] = fmaf(a0.x, m0.x, t0[0]); t1[0] = fmaf(a0.x, m0.y, t1[0]);
            t0[0] = fmaf(a0.y, m1.x, t0[0]); t1[0] = fmaf(a0.y, m1.y, t1[0]);
            t0[0] = fmaf(a0.z, m2.x, t0[0]); t1[0] = fmaf(a0.z, m2.y, t1[0]);
            t0[0] = fmaf(a0.w, m3.x, t0[0]); t1[0] = fmaf(a0.w, m3.y, t1[0]);
            t0[1] = fmaf(a1.x, m0.x, t0[1]); t1[1] = fmaf(a1.x, m0.y, t1[1]);
            t0[1] = fmaf(a1.y, m1.x, t0[1]); t1[1] = fmaf(a1.y, m1.y, t1[1]);
            t0[1] = fmaf(a1.z, m2.x, t0[1]); t1[1] = fmaf(a1.z, m2.y, t1[1]);
            t0[1] = fmaf(a1.w, m3.x, t0[1]); t1[1] = fmaf(a1.w, m3.y, t1[1]);
        }

        // scores (partial over this lane's col pair), then butterfly
        float vx[2][EE], vy[2][EE], sc[2][EE];
        #pragma unroll
        for (int j = 0; j < 2; ++j)
            #pragma unroll
            for (int e = 0; e < EE; ++e) {
                float2 v = *(const float2*)&lds[slab + j * 768 + (1 + e) * DD + c0];
                vx[j][e] = v.x; vy[j][e] = v.y;
                sc[j][e] = t0[j] * v.x + t1[j] * v.y;
            }
        #pragma unroll
        for (int off = 32; off > 0; off >>= 1)
            #pragma unroll
            for (int j = 0; j < 2; ++j)
                #pragma unroll
                for (int e = 0; e < EE; ++e)
                    sc[j][e] += __shfl_xor(sc[j][e], off, 64);

        float alpha[2][EE];
        #pragma unroll
        for (int j = 0; j < 2; ++j) {
            float mx = sc[j][0];
            #pragma unroll
            for (int e = 1; e < EE; ++e) mx = fmaxf(mx, sc[j][e]);
            float sum = 0.f;
            #pragma unroll
            for (int e = 0; e < EE; ++e) { alpha[j][e] = expf(sc[j][e] - mx); sum += alpha[j][e]; }
            const float inv = 1.f / sum;
            #pragma unroll
            for (int e = 0; e < EE; ++e) alpha[j][e] *= inv;
        }

        // logits (partial over col pair), butterfly
        float Lg[2][NOUT];
        #pragma unroll
        for (int j = 0; j < 2; ++j) {
            float2 a2 = *(const float2*)&lds[slab + j * 768 + c0];
            #pragma unroll
            for (int o = 0; o < NOUT; ++o) {
                float2 w1 = *(const float2*)&ws[WS_W1T + o * DD + c0];
                Lg[j][o] = fmaf(a2.x, w1.x, a2.y * w1.y);
            }
        }
        #pragma unroll
        for (int e = 0; e < EE; ++e) {
            float wxj[2], wyj[2];
            #pragma unroll
            for (int j = 0; j < 2; ++j) { wxj[j] = alpha[j][e] * vx[j][e]; wyj[j] = alpha[j][e] * vy[j][e]; }
            #pragma unroll
            for (int o = 0; o < NOUT; ++o) {
                float2 f2 = *(const float2*)&ws[WS_F2T + (e * NOUT + o) * DD + c0];
                #pragma unroll
                for (int j = 0; j < 2; ++j)
                    Lg[j][o] = fmaf(wxj[j], f2.x, fmaf(wyj[j], f2.y, Lg[j][o]));
            }
        }
        #pragma unroll
        for (int off = 32; off > 0; off >>= 1)
            #pragma unroll
            for (int j = 0; j < 2; ++j)
                #pragma unroll
                for (int o = 0; o < NOUT; ++o)
                    Lg[j][o] += __shfl_xor(Lg[j][o], off, 64);

        // Gumbel + argmax (monotone -> skip softmax/tau)
        const int S0 = bs0 + w * 4 + 2 * p;
        float y = -1e30f;
        if (lane < 10) {
            const int jl = lane / 5, ol = lane - 5 * jl;
            const float uu  = u[(size_t)S0 * NOUT + lane];      // contiguous over both samples
            const float gmb = -logf(-logf(uu + 1e-10f) + 1e-10f);
            y = Lg[jl][ol] + fc_b[ol] + gmb;
        }
        float b0 = -1e30f, b1 = -1e30f; int bi0 = 0, bi1 = 0;
        #pragma unroll
        for (int o = 0; o < NOUT; ++o) {
            float y0 = __shfl(y, o, 64);
            float y1 = __shfl(y, 5 + o, 64);
            if (y0 > b0) { b0 = y0; bi0 = o; }   // strict > == np.argmax first-max
            if (y1 > b1) { b1 = y1; bi1 = o; }
        }
        if (lane < 2) out[S0 + lane] = lane ? bi1 : bi0;
    }
}

extern "C" void kernel_launch(void* const* d_in, const int* in_sizes, int n_in,
                              void* d_out, int out_size, void* d_ws, size_t ws_size,
                              hipStream_t stream) {
    const float* obs   = (const float*)d_in[0];
    const float* enc_w = (const float*)d_in[1];
    const float* enc_b = (const float*)d_in[2];
    const float* q_w   = (const float*)d_in[3];
    const float* k_w   = (const float*)d_in[4];
    const float* fc_w  = (const float*)d_in[5];
    const float* fc_b  = (const float*)d_in[6];
    const float* uu    = (const float*)d_in[7];
    float* ws = (float*)d_ws;
    int*   po = (int*)d_out;

    precompute_kernel<<<129, 128, 0, stream>>>(q_w, k_w, fc_w, ws);
    policy_kernel<<<NB / SBLK, 256, 0, stream>>>(obs, enc_w, enc_b, fc_b, uu, ws, po);
}

// Round 6
// 403.836 us; speedup vs baseline: 1.3089x; 1.3089x over previous
//
#include <hip/hip_runtime.h>
#include <math.h>

// Problem constants
#define NB   32768
#define AG   6
#define LL   225
#define DD   128
#define EE   5
#define NOUT 5
#define ADIM 64

// Workspace layout
#define WS_M        0        // floats: 128*128  M = q_w@k_w^T / 8
#define WS_W1T      16384    // floats: 5*128
#define WS_F2T      17024    // floats: 25*128
#define WS_BSWZ_B   80896    // bytes: B_swz = 8kb*8nt*3s*64lane*8 bf16 = 196608 B

// Encoder-as-MFMA tiling: block = 256 thr = 4 waves, 16 samples = 96 rows.
// M-tiles: 6 (16 rows each). N-tiles: 8 (16 cols); wave w owns nt {2w,2w+1}.
// K = 225 padded to 256 = 8 K-steps of 32, staged in 4 chunks of 64.
#define SBLK 16
#define NKB  8
#define ENC_STRIDE 132       // enc LDS row stride (pad: 4*132 % 32 = 16 -> 2-way free)
#define LDS_FLOATS 12672     // max(A_swz 36864 B, enc 96*132*4 = 50688 B) = 50688 B

typedef __attribute__((ext_vector_type(8))) short short8v;
typedef __attribute__((ext_vector_type(4))) float float4v;

// bf16 RNE split helper: returns bf16 bits of x, *rem = x - bf16(x) (exact)
__device__ __forceinline__ unsigned short bf_hi(float x, float* rem) {
    unsigned u = __float_as_uint(x);
    unsigned r = (u + 0x7FFFu + ((u >> 16) & 1u)) & 0xFFFF0000u;
    *rem = x - __uint_as_float(r);
    return (unsigned short)(r >> 16);
}

// A_swz slot (in ushorts): [kbL][mt][split][lane] * 8 elements
__device__ __forceinline__ int aslot(int kbL, int mt, int s, int la) {
    return ((((kbL * 6 + mt) * 3 + s) * 64) + la) * 8;
}

__global__ void precompute_kernel(const float* __restrict__ q_w,
                                  const float* __restrict__ k_w,
                                  const float* __restrict__ enc_w,
                                  const float* __restrict__ fc_w,
                                  float* __restrict__ ws) {
    int b = blockIdx.x;
    int t = threadIdx.x;
    if (b < 128) {
        float s = 0.f;
        #pragma unroll 8
        for (int j = 0; j < ADIM; ++j)
            s = fmaf(q_w[b * ADIM + j], k_w[t * ADIM + j], s);
        ws[WS_M + b * 128 + t] = s * 0.125f;
    } else if (b == 128) {
        int d = t;
        #pragma unroll
        for (int o = 0; o < NOUT; ++o) {
            float s = 0.f;
            #pragma unroll
            for (int e = 0; e < EE; ++e)
                s += fc_w[(e * 128 + d) * NOUT + o];
            ws[WS_W1T + o * 128 + d] = s;
            #pragma unroll
            for (int e = 0; e < EE; ++e)
                ws[WS_F2T + (e * 5 + o) * 128 + d] = fc_w[(640 + e * 128 + d) * NOUT + o];
        }
    } else {
        // B_swz: enc_w -> bf16x3, MFMA B-frag order.
        // B-frag (16x16x32): lane holds B[k = (lane>>4)*8 + j][n = lane&15], j=0..7
        int idx = (b - 129) * 128 + t;          // 0..12287 = kb*8nt*3s*64lane
        int lane = idx & 63;
        int rest = idx >> 6;                    // 0..191
        int s    = rest % 3;
        int r2   = rest / 3;                    // 0..63
        int nt   = r2 & 7;
        int kb   = r2 >> 3;
        unsigned short* bs = (unsigned short*)((char*)ws + WS_BSWZ_B);
        const int n     = nt * 16 + (lane & 15);
        const int kbase = kb * 32 + (lane >> 4) * 8;
        #pragma unroll
        for (int j = 0; j < 8; ++j) {
            int k = kbase + j;
            float x = (k < LL) ? enc_w[k * DD + n] : 0.f;
            float q1, q2, q3;
            unsigned short h = bf_hi(x,  &q1);
            unsigned short m = bf_hi(q1, &q2);
            unsigned short l = bf_hi(q2, &q3);
            bs[(((kb * 8 + nt) * 3 + s) * 64 + lane) * 8 + j] =
                (s == 0) ? h : (s == 1) ? m : l;
        }
    }
}

__global__ __launch_bounds__(256, 2)
void policy_kernel(const float* __restrict__ obs,
                   const float* __restrict__ enc_b,
                   const float* __restrict__ fc_b,
                   const float* __restrict__ u,
                   const float* __restrict__ ws,
                   int* __restrict__ out) {
    __shared__ float lds[LDS_FLOATS];
    unsigned short* aswz = (unsigned short*)lds;

    const int tid  = threadIdx.x;
    const int lane = tid & 63;
    const int w    = tid >> 6;
    const int bs0  = blockIdx.x * SBLK;
    const float* obs_blk = obs + (size_t)bs0 * (AG * LL);
    const unsigned short* bswz = (const unsigned short*)((const char*)ws + WS_BSWZ_B);

    // ---- encoder: C[96][128] = obs[96][256pad] @ enc_w[256pad][128], bf16x3 ----
    float4v acc[6][2];
    #pragma unroll
    for (int mt = 0; mt < 6; ++mt)
        #pragma unroll
        for (int nt = 0; nt < 2; ++nt)
            acc[mt][nt] = (float4v){0.f, 0.f, 0.f, 0.f};

    #pragma unroll 1
    for (int c = 0; c < 4; ++c) {
        const int k0 = 64 * c;
        // ---- stage A chunk: rows 0..95, k = k0..k0+63 -> bf16x3 frag order ----
        #pragma unroll
        for (int rr = 0; rr < 6; ++rr) {
            const int r  = rr * 16 + (tid >> 4);
            const int k4 = tid & 15;
            const int k  = k0 + 4 * k4;
            float4 v = make_float4(0.f, 0.f, 0.f, 0.f);
            if (k + 3 <= 224)      v = *(const float4*)&obs_blk[r * LL + k];
            else if (k == 224)     v.x = obs_blk[r * LL + 224];
            float vf[4] = {v.x, v.y, v.z, v.w};
            unsigned long long ph = 0, pm = 0, pl = 0;
            #pragma unroll
            for (int e = 0; e < 4; ++e) {
                float q1, q2, q3;
                unsigned short h = bf_hi(vf[e], &q1);
                unsigned short m = bf_hi(q1,    &q2);
                unsigned short l = bf_hi(q2,    &q3);
                ph |= (unsigned long long)h << (16 * e);
                pm |= (unsigned long long)m << (16 * e);
                pl |= (unsigned long long)l << (16 * e);
            }
            const int mt  = r >> 4, mm = r & 15;
            const int kbL = k4 >> 3;
            const int kk  = (4 * k4) & 31;
            const int la  = mm + 16 * (kk >> 3);
            const int j0  = kk & 7;              // 0 or 4
            *(unsigned long long*)&aswz[aslot(kbL, mt, 0, la) + j0] = ph;
            *(unsigned long long*)&aswz[aslot(kbL, mt, 1, la) + j0] = pm;
            *(unsigned long long*)&aswz[aslot(kbL, mt, 2, la) + j0] = pl;
        }
        __syncthreads();

        // ---- MFMA over the 2 K-steps of this chunk ----
        #pragma unroll
        for (int kbL = 0; kbL < 2; ++kbL) {
            const int kb = 2 * c + kbL;
            short8v Bf[2][3];
            #pragma unroll
            for (int nt = 0; nt < 2; ++nt)
                #pragma unroll
                for (int s = 0; s < 3; ++s)
                    Bf[nt][s] = *(const short8v*)
                        &bswz[(((kb * 8 + (2 * w + nt)) * 3 + s) * 64 + lane) * 8];
            #pragma unroll
            for (int mt = 0; mt < 6; ++mt) {
                short8v Ah = *(const short8v*)&aswz[aslot(kbL, mt, 0, lane)];
                short8v Am = *(const short8v*)&aswz[aslot(kbL, mt, 1, lane)];
                short8v Al = *(const short8v*)&aswz[aslot(kbL, mt, 2, lane)];
                #pragma unroll
                for (int nt = 0; nt < 2; ++nt) {
                    float4v d = acc[mt][nt];
                    d = __builtin_amdgcn_mfma_f32_16x16x32_bf16(Ah, Bf[nt][0], d, 0, 0, 0);
                    d = __builtin_amdgcn_mfma_f32_16x16x32_bf16(Ah, Bf[nt][1], d, 0, 0, 0);
                    d = __builtin_amdgcn_mfma_f32_16x16x32_bf16(Am, Bf[nt][0], d, 0, 0, 0);
                    d = __builtin_amdgcn_mfma_f32_16x16x32_bf16(Ah, Bf[nt][2], d, 0, 0, 0);
                    d = __builtin_amdgcn_mfma_f32_16x16x32_bf16(Al, Bf[nt][0], d, 0, 0, 0);
                    d = __builtin_amdgcn_mfma_f32_16x16x32_bf16(Am, Bf[nt][1], d, 0, 0, 0);
                    acc[mt][nt] = d;
                }
            }
        }
        __syncthreads();   // A_swz dead before next chunk's staging (or enc write)
    }

    // ---- unload C tiles -> enc LDS [96][132] with bias+relu ----
    // C/D layout (verified m89): col = lane&15, row = (lane>>4)*4 + reg
    {
        #pragma unroll
        for (int nt = 0; nt < 2; ++nt) {
            const int col = (2 * w + nt) * 16 + (lane & 15);
            const float bb = enc_b[col];
            #pragma unroll
            for (int mt = 0; mt < 6; ++mt) {
                const int rbase = mt * 16 + (lane >> 4) * 4;
                #pragma unroll
                for (int reg = 0; reg < 4; ++reg)
                    lds[(rbase + reg) * ENC_STRIDE + col] =
                        fmaxf(acc[mt][nt][reg] + bb, 0.f);
            }
        }
    }
    __syncthreads();

    // ---- phase 2 (r5-verified structure; enc read from block LDS) ----
    const float* Mw = ws + WS_M;
    const int c0 = 2 * lane;

    #pragma unroll 1
    for (int p = 0; p < 2; ++p) {
        const int sA = 4 * w + 2 * p;        // block-local samples sA, sA+1
        const int rA = sA * AG;              // enc row of agent 0
        const int rB = (sA + 1) * AG;

        // t = ag_e @ M for both samples
        float t0[2] = {0.f, 0.f}, t1[2] = {0.f, 0.f};
        #pragma unroll 4
        for (int d = 0; d < DD; d += 4) {
            float4 a0 = *(const float4*)&lds[rA * ENC_STRIDE + d];
            float4 a1 = *(const float4*)&lds[rB * ENC_STRIDE + d];
            float2 m0 = *(const float2*)&Mw[(size_t)(d + 0) * DD + c0];
            float2 m1 = *(const float2*)&Mw[(size_t)(d + 1) * DD + c0];
            float2 m2 = *(const float2*)&Mw[(size_t)(d + 2) * DD + c0];
            float2 m3 = *(const float2*)&Mw[(size_t)(d + 3) * DD + c0];
            t0[0] = fmaf(a0.x, m0.x, t0[0]); t1[0] = fmaf(a0.x, m0.y, t1[0]);
            t0[0] = fmaf(a0.y, m1.x, t0[0]); t1[0] = fmaf(a0.y, m1.y, t1[0]);
            t0[0] = fmaf(a0.z, m2.x, t0[0]); t1[0] = fmaf(a0.z, m2.y, t1[0]);
            t0[0] = fmaf(a0.w, m3.x, t0[0]); t1[0] = fmaf(a0.w, m3.y, t1[0]);
            t0[1] = fmaf(a1.x, m0.x, t0[1]); t1[1] = fmaf(a1.x, m0.y, t1[1]);
            t0[1] = fmaf(a1.y, m1.x, t0[1]); t1[1] = fmaf(a1.y, m1.y, t1[1]);
            t0[1] = fmaf(a1.z, m2.x, t0[1]); t1[1] = fmaf(a1.z, m2.y, t1[1]);
            t0[1] = fmaf(a1.w, m3.x, t0[1]); t1[1] = fmaf(a1.w, m3.y, t1[1]);
        }

        // scores (partial over this lane's col pair), then butterfly
        float vx[2][EE], vy[2][EE], sc[2][EE];
        #pragma unroll
        for (int j = 0; j < 2; ++j)
            #pragma unroll
            for (int e = 0; e < EE; ++e) {
                float2 v = *(const float2*)&lds[((sA + j) * AG + 1 + e) * ENC_STRIDE + c0];
                vx[j][e] = v.x; vy[j][e] = v.y;
                sc[j][e] = t0[j] * v.x + t1[j] * v.y;
            }
        #pragma unroll
        for (int off = 32; off > 0; off >>= 1)
            #pragma unroll
            for (int j = 0; j < 2; ++j)
                #pragma unroll
                for (int e = 0; e < EE; ++e)
                    sc[j][e] += __shfl_xor(sc[j][e], off, 64);

        float alpha[2][EE];
        #pragma unroll
        for (int j = 0; j < 2; ++j) {
            float mx = sc[j][0];
            #pragma unroll
            for (int e = 1; e < EE; ++e) mx = fmaxf(mx, sc[j][e]);
            float sum = 0.f;
            #pragma unroll
            for (int e = 0; e < EE; ++e) { alpha[j][e] = expf(sc[j][e] - mx); sum += alpha[j][e]; }
            const float inv = 1.f / sum;
            #pragma unroll
            for (int e = 0; e < EE; ++e) alpha[j][e] *= inv;
        }

        // logits (partial over col pair), butterfly
        float Lg[2][NOUT];
        #pragma unroll
        for (int j = 0; j < 2; ++j) {
            float2 a2 = *(const float2*)&lds[(sA + j) * AG * ENC_STRIDE + c0];
            #pragma unroll
            for (int o = 0; o < NOUT; ++o) {
                float2 w1 = *(const float2*)&ws[WS_W1T + o * DD + c0];
                Lg[j][o] = fmaf(a2.x, w1.x, a2.y * w1.y);
            }
        }
        #pragma unroll
        for (int e = 0; e < EE; ++e) {
            float wxj[2], wyj[2];
            #pragma unroll
            for (int j = 0; j < 2; ++j) { wxj[j] = alpha[j][e] * vx[j][e]; wyj[j] = alpha[j][e] * vy[j][e]; }
            #pragma unroll
            for (int o = 0; o < NOUT; ++o) {
                float2 f2 = *(const float2*)&ws[WS_F2T + (e * NOUT + o) * DD + c0];
                #pragma unroll
                for (int j = 0; j < 2; ++j)
                    Lg[j][o] = fmaf(wxj[j], f2.x, fmaf(wyj[j], f2.y, Lg[j][o]));
            }
        }
        #pragma unroll
        for (int off = 32; off > 0; off >>= 1)
            #pragma unroll
            for (int j = 0; j < 2; ++j)
                #pragma unroll
                for (int o = 0; o < NOUT; ++o)
                    Lg[j][o] += __shfl_xor(Lg[j][o], off, 64);

        // Gumbel + argmax (monotone -> skip softmax/tau)
        const int S0 = bs0 + sA;
        float y = -1e30f;
        if (lane < 10) {
            const int jl = lane / 5, ol = lane - 5 * jl;
            const float uu  = u[(size_t)S0 * NOUT + lane];
            const float gmb = -logf(-logf(uu + 1e-10f) + 1e-10f);
            y = Lg[jl][ol] + fc_b[ol] + gmb;
        }
        float b0 = -1e30f, b1 = -1e30f; int bi0 = 0, bi1 = 0;
        #pragma unroll
        for (int o = 0; o < NOUT; ++o) {
            float y0 = __shfl(y, o, 64);
            float y1 = __shfl(y, 5 + o, 64);
            if (y0 > b0) { b0 = y0; bi0 = o; }   // strict > == np.argmax first-max
            if (y1 > b1) { b1 = y1; bi1 = o; }
        }
        if (lane < 2) out[S0 + lane] = lane ? bi1 : bi0;
    }
}

extern "C" void kernel_launch(void* const* d_in, const int* in_sizes, int n_in,
                              void* d_out, int out_size, void* d_ws, size_t ws_size,
                              hipStream_t stream) {
    const float* obs   = (const float*)d_in[0];
    const float* enc_w = (const float*)d_in[1];
    const float* enc_b = (const float*)d_in[2];
    const float* q_w   = (const float*)d_in[3];
    const float* k_w   = (const float*)d_in[4];
    const float* fc_w  = (const float*)d_in[5];
    const float* fc_b  = (const float*)d_in[6];
    const float* uu    = (const float*)d_in[7];
    float* ws = (float*)d_ws;
    int*   po = (int*)d_out;

    precompute_kernel<<<225, 128, 0, stream>>>(q_w, k_w, enc_w, fc_w, ws);
    policy_kernel<<<NB / SBLK, 256, 0, stream>>>(obs, enc_b, fc_b, uu, ws, po);
}